// Round 2
// baseline (120.045 us; speedup 1.0000x reference)
//
#include <hip/hip_runtime.h>

// LSTM, T=2^20 steps, H=4. Speculative chunked scan:
//   - K chunks of C=64 output steps each; each chunk warm-starts from (h,c)=(0,0)
//     W=512 steps earlier (clamped to 0 => exact for early chunks). The LSTM map
//     is contracting (sigmoid forget gate + saturated activations), so the
//     warm-up error decays ~e^{-0.2*W} -> far below the 2e-2 threshold.
//   - One chunk per 4-lane quad. Lane k owns hidden index k: computes gate rows
//     {k, 4+k, 8+k, 12+k} (i,f,g,o), c_k, h_k locally. The only cross-lane op is
//     broadcasting h (3 quad_perm DPP moves, VALU speed, no LDS).
//   - W_hh columns are pre-permuted per-lane by XOR so gate = sum_m Whh[t][m]*hx[m]
//     with hx[m] = h[lane^m] (static register indexing only).
//   - x loads are prefetched one 8-step batch ahead to hide memory latency.

constexpr int T_LEN  = 1 << 20;
constexpr int CHUNK  = 64;
constexpr int WARM   = 512;
constexpr int NCHUNK = T_LEN / CHUNK;      // 16384
constexpr int BLOCK  = 64;
constexpr int GRID   = NCHUNK * 4 / BLOCK; // 1024 blocks = 1 wave/SIMD chip-wide

// quad_perm DPP: dest lane i (within each 4-lane quad) reads src lane sel_i.
// xor1: [1,0,3,2] = 0xB1 ; xor2: [2,3,0,1] = 0x4E ; xor3: [3,2,1,0] = 0x1B
template <int CTRL>
__device__ __forceinline__ float qperm(float v) {
    int i = __float_as_int(v);
    i = __builtin_amdgcn_update_dpp(i, i, CTRL, 0xF, 0xF, false);
    return __int_as_float(i);
}

// v_rcp_f32 is ~1ulp; avoids the precise-division expansion (div_scale/fmas/fixup).
__device__ __forceinline__ float sigmoid_f(float x) {
    return __builtin_amdgcn_rcpf(1.0f + __expf(-x));
}
__device__ __forceinline__ float tanh_f(float x) {
    // 1 - 2/(e^{2x}+1); stable at both extremes (inf -> 1, 0 -> -1).
    return 1.0f - 2.0f * __builtin_amdgcn_rcpf(__expf(2.0f * x) + 1.0f);
}

__global__ __launch_bounds__(BLOCK, 1) void lstm_chunks(
    const float* __restrict__ x,    // [T,4]
    const float* __restrict__ Wih,  // [16,4]
    const float* __restrict__ Whh,  // [16,4]
    const float* __restrict__ bih,  // [16]
    const float* __restrict__ bhh,  // [16]
    const float* __restrict__ h0,   // [4]
    const float* __restrict__ c0,   // [4]
    float* __restrict__ out)        // [T,4]
{
    const int tid   = blockIdx.x * BLOCK + threadIdx.x;
    const int lane  = tid & 3;   // hidden index k owned by this lane
    const int chunk = tid >> 2;

    // Per-lane weights. Gate type t in {i,f,g,o} -> packed row r = t*4 + lane.
    // whh columns permuted: whh[t][m] multiplies hx[m] = h[lane ^ m].
    float wih[4][4], whh[4][4], bias[4];
#pragma unroll
    for (int t = 0; t < 4; ++t) {
        const int r = t * 4 + lane;
#pragma unroll
        for (int m = 0; m < 4; ++m) {
            wih[t][m] = Wih[r * 4 + m];
            whh[t][m] = Whh[r * 4 + (lane ^ m)];
        }
        bias[t] = bih[r] + bhh[r];
    }

    const int tout0 = chunk * CHUNK;
    const int tend  = tout0 + CHUNK;
    int t0 = tout0 - WARM;
    if (t0 < 0) t0 = 0;            // early chunks start exactly at t=0

    float hx0, hx1, hx2, hx3, c;
    if (t0 == 0) {                 // exact initial state
        hx0 = h0[lane];
        hx1 = h0[lane ^ 1];
        hx2 = h0[lane ^ 2];
        hx3 = h0[lane ^ 3];
        c   = c0[lane];
    } else {                       // speculative zero state + warmup
        hx0 = hx1 = hx2 = hx3 = 0.0f;
        c = 0.0f;
    }

    // Prefetched x batches: 8 steps = 128B per quad (one cacheline).
    float4 buf[8];
#pragma unroll
    for (int u = 0; u < 8; ++u)
        buf[u] = *reinterpret_cast<const float4*>(x + 4 * (t0 + u));

    // Trip count (tend - t0) is always a multiple of 8.
    for (int tb = t0; tb < tend; tb += 8) {
        float4 nbuf[8];
#pragma unroll
        for (int u = 0; u < 8; ++u) {
            int tn = tb + 8 + u;
            tn = tn < T_LEN ? tn : T_LEN - 1;   // clamp final prefetch
            nbuf[u] = *reinterpret_cast<const float4*>(x + 4 * tn);
        }
#pragma unroll
        for (int u = 0; u < 8; ++u) {
            const int t  = tb + u;
            const float4 xv = buf[u];
            // gates, packed-row order i,f,g,o
            float g0 = bias[0] + wih[0][0]*xv.x + wih[0][1]*xv.y + wih[0][2]*xv.z + wih[0][3]*xv.w;
            float g1 = bias[1] + wih[1][0]*xv.x + wih[1][1]*xv.y + wih[1][2]*xv.z + wih[1][3]*xv.w;
            float g2 = bias[2] + wih[2][0]*xv.x + wih[2][1]*xv.y + wih[2][2]*xv.z + wih[2][3]*xv.w;
            float g3 = bias[3] + wih[3][0]*xv.x + wih[3][1]*xv.y + wih[3][2]*xv.z + wih[3][3]*xv.w;
            g0 += whh[0][0]*hx0 + whh[0][1]*hx1 + whh[0][2]*hx2 + whh[0][3]*hx3;
            g1 += whh[1][0]*hx0 + whh[1][1]*hx1 + whh[1][2]*hx2 + whh[1][3]*hx3;
            g2 += whh[2][0]*hx0 + whh[2][1]*hx1 + whh[2][2]*hx2 + whh[2][3]*hx3;
            g3 += whh[3][0]*hx0 + whh[3][1]*hx1 + whh[3][2]*hx2 + whh[3][3]*hx3;

            const float i_ = sigmoid_f(g0);
            const float f_ = sigmoid_f(g1);
            const float gg = tanh_f(g2);
            const float o_ = sigmoid_f(g3);

            c = f_ * c + i_ * gg;
            const float hk = o_ * tanh_f(c);

            // broadcast h within the quad (all 4 lanes of a quad share a chunk,
            // so exec is quad-uniform here even when wave lanes diverge on trip count)
            hx0 = hk;
            hx1 = qperm<0xB1>(hk);
            hx2 = qperm<0x4E>(hk);
            hx3 = qperm<0x1B>(hk);

            if (t >= tout0) out[4 * t + lane] = hk;
        }
#pragma unroll
        for (int u = 0; u < 8; ++u) buf[u] = nbuf[u];
    }
}

extern "C" void kernel_launch(void* const* d_in, const int* in_sizes, int n_in,
                              void* d_out, int out_size, void* d_ws, size_t ws_size,
                              hipStream_t stream) {
    const float* x   = (const float*)d_in[0];
    const float* Wih = (const float*)d_in[1];
    const float* Whh = (const float*)d_in[2];
    const float* bih = (const float*)d_in[3];
    const float* bhh = (const float*)d_in[4];
    const float* h0  = (const float*)d_in[5];
    const float* c0  = (const float*)d_in[6];
    float* out = (float*)d_out;

    hipLaunchKernelGGL(lstm_chunks, dim3(GRID), dim3(BLOCK), 0, stream,
                       x, Wih, Whh, bih, bhh, h0, c0, out);
}

// Round 3
// 45.366 us; speedup vs baseline: 2.6461x; 2.6461x over previous
//
#include <hip/hip_runtime.h>

// LSTM, T=2^20, H=4. Speculative chunked scan (round 2).
//   - NCHUNK=16384 chunks of CHUNK=64 outputs; each warm-starts (h,c)=(0,0)
//     WARM=128 steps earlier (clamped to 0). Contraction: E[ln f] ~ -1.1/step
//     => warmup error ~e^-140, far below the 2e-2 threshold. Round-1 evidence:
//     WARM=512 gave absmax exactly 2^-8 (bf16 compare floor, not warmup error).
//   - One chunk per 4-lane quad; lane k owns hidden k. Cross-lane = 3 quad_perm
//     DPP broadcasts of h. W_hh pre-permuted per-lane (XOR) for static indexing.
//   - Split warmup loop (no store/compare) from output loop.
//   - Double-buffered 4-step x prefetch (2x16B/lane in flight), ~2000cy ahead.
//   - Nontemporal h stores: don't evict the x working set from L2.

constexpr int T_LEN  = 1 << 20;
constexpr int CHUNK  = 64;
constexpr int WARM   = 128;
constexpr int NCHUNK = T_LEN / CHUNK;       // 16384
constexpr int BLOCK  = 64;
constexpr int GRID   = NCHUNK * 4 / BLOCK;  // 1024 waves = 1 per SIMD chip-wide

// quad_perm DPP: xor1=[1,0,3,2]=0xB1, xor2=[2,3,0,1]=0x4E, xor3=[3,2,1,0]=0x1B
template <int CTRL>
__device__ __forceinline__ float qperm(float v) {
    int i = __float_as_int(v);
    i = __builtin_amdgcn_update_dpp(i, i, CTRL, 0xF, 0xF, false);
    return __int_as_float(i);
}

__device__ __forceinline__ float sigmoid_f(float x) {
    return __builtin_amdgcn_rcpf(1.0f + __expf(-x));
}

struct LaneState { float hx0, hx1, hx2, hx3, c; };

__device__ __forceinline__ float lstm_step(
    const float4 xv,
    const float (&wih)[4][4], const float (&whh)[4][4], const float (&bias)[4],
    LaneState& s)
{
    // x-part: off the critical path (prefetched), minimize instr count: 4 fma chain.
    float g0 = __builtin_fmaf(wih[0][3], xv.w, __builtin_fmaf(wih[0][2], xv.z,
               __builtin_fmaf(wih[0][1], xv.y, __builtin_fmaf(wih[0][0], xv.x, bias[0]))));
    float g1 = __builtin_fmaf(wih[1][3], xv.w, __builtin_fmaf(wih[1][2], xv.z,
               __builtin_fmaf(wih[1][1], xv.y, __builtin_fmaf(wih[1][0], xv.x, bias[1]))));
    float g2 = __builtin_fmaf(wih[2][3], xv.w, __builtin_fmaf(wih[2][2], xv.z,
               __builtin_fmaf(wih[2][1], xv.y, __builtin_fmaf(wih[2][0], xv.x, bias[2]))));
    float g3 = __builtin_fmaf(wih[3][3], xv.w, __builtin_fmaf(wih[3][2], xv.z,
               __builtin_fmaf(wih[3][1], xv.y, __builtin_fmaf(wih[3][0], xv.x, bias[3]))));
    // h-part: critical path; hx0 (local, earliest-ready) first.
    g0 = __builtin_fmaf(whh[0][3], s.hx3, __builtin_fmaf(whh[0][2], s.hx2,
         __builtin_fmaf(whh[0][1], s.hx1, __builtin_fmaf(whh[0][0], s.hx0, g0))));
    g1 = __builtin_fmaf(whh[1][3], s.hx3, __builtin_fmaf(whh[1][2], s.hx2,
         __builtin_fmaf(whh[1][1], s.hx1, __builtin_fmaf(whh[1][0], s.hx0, g1))));
    g2 = __builtin_fmaf(whh[2][3], s.hx3, __builtin_fmaf(whh[2][2], s.hx2,
         __builtin_fmaf(whh[2][1], s.hx1, __builtin_fmaf(whh[2][0], s.hx0, g2))));
    g3 = __builtin_fmaf(whh[3][3], s.hx3, __builtin_fmaf(whh[3][2], s.hx2,
         __builtin_fmaf(whh[3][1], s.hx1, __builtin_fmaf(whh[3][0], s.hx0, g3))));

    const float i_ = sigmoid_f(g0);
    const float f_ = sigmoid_f(g1);
    const float gg = __builtin_fmaf(-2.0f,
                       __builtin_amdgcn_rcpf(__expf(2.0f * g2) + 1.0f), 1.0f);
    const float o_ = sigmoid_f(g3);

    s.c = __builtin_fmaf(f_, s.c, i_ * gg);
    const float th = __builtin_fmaf(-2.0f,
                       __builtin_amdgcn_rcpf(__expf(2.0f * s.c) + 1.0f), 1.0f);
    const float hk = o_ * th;

    s.hx0 = hk;
    s.hx1 = qperm<0xB1>(hk);
    s.hx2 = qperm<0x4E>(hk);
    s.hx3 = qperm<0x1B>(hk);
    return hk;
}

__global__ __launch_bounds__(BLOCK, 1) void lstm_chunks(
    const float* __restrict__ x,    // [T,4]
    const float* __restrict__ Wih,  // [16,4]
    const float* __restrict__ Whh,  // [16,4]
    const float* __restrict__ bih,  // [16]
    const float* __restrict__ bhh,  // [16]
    const float* __restrict__ h0,   // [4]
    const float* __restrict__ c0,   // [4]
    float* __restrict__ out)        // [T,4]
{
    const int tid   = blockIdx.x * BLOCK + threadIdx.x;
    const int lane  = tid & 3;
    const int chunk = tid >> 2;

    float wih[4][4], whh[4][4], bias[4];
#pragma unroll
    for (int t = 0; t < 4; ++t) {
        const int r = t * 4 + lane;
#pragma unroll
        for (int m = 0; m < 4; ++m) {
            wih[t][m] = Wih[r * 4 + m];
            whh[t][m] = Whh[r * 4 + (lane ^ m)];
        }
        bias[t] = bih[r] + bhh[r];
    }

    const int tout0 = chunk * CHUNK;
    const int tend  = tout0 + CHUNK;
    int t0 = tout0 - WARM;
    if (t0 < 0) t0 = 0;             // early chunks start exactly at t=0

    LaneState s;
    if (t0 == 0) {
        s.hx0 = h0[lane];  s.hx1 = h0[lane ^ 1];
        s.hx2 = h0[lane ^ 2]; s.hx3 = h0[lane ^ 3];
        s.c = c0[lane];
    } else {
        s.hx0 = s.hx1 = s.hx2 = s.hx3 = 0.0f;
        s.c = 0.0f;
    }

    float4 bufA[4], bufB[4];
#pragma unroll
    for (int u = 0; u < 4; ++u)
        bufA[u] = *reinterpret_cast<const float4*>(x + 4 * (t0 + u));

    // ---- warmup (no stores). Trip count in {0, 64, 128}: multiple of 8. ----
    for (int tb = t0; tb < tout0; tb += 8) {
#pragma unroll
        for (int u = 0; u < 4; ++u)
            bufB[u] = *reinterpret_cast<const float4*>(x + 4 * (tb + 4 + u));
#pragma unroll
        for (int u = 0; u < 4; ++u) (void)lstm_step(bufA[u], wih, whh, bias, s);
#pragma unroll
        for (int u = 0; u < 4; ++u)
            bufA[u] = *reinterpret_cast<const float4*>(x + 4 * (tb + 8 + u));
#pragma unroll
        for (int u = 0; u < 4; ++u) (void)lstm_step(bufB[u], wih, whh, bias, s);
    }

    // ---- output loop: CHUNK=64 steps, unconditional nontemporal stores. ----
    float* po = out + 4 * tout0 + lane;
    for (int tb = tout0; tb < tend; tb += 8) {
#pragma unroll
        for (int u = 0; u < 4; ++u) {
            int tn = tb + 4 + u;                    // clamp: only last chunk overruns
            tn = tn < T_LEN ? tn : T_LEN - 1;
            bufB[u] = *reinterpret_cast<const float4*>(x + 4 * tn);
        }
#pragma unroll
        for (int u = 0; u < 4; ++u) {
            const float hk = lstm_step(bufA[u], wih, whh, bias, s);
            __builtin_nontemporal_store(hk, po + 4 * (tb - tout0 + u));
        }
#pragma unroll
        for (int u = 0; u < 4; ++u) {
            int tn = tb + 8 + u;
            tn = tn < T_LEN ? tn : T_LEN - 1;
            bufA[u] = *reinterpret_cast<const float4*>(x + 4 * tn);
        }
#pragma unroll
        for (int u = 0; u < 4; ++u) {
            const float hk = lstm_step(bufB[u], wih, whh, bias, s);
            __builtin_nontemporal_store(hk, po + 4 * (tb - tout0 + 4 + u));
        }
    }
}

extern "C" void kernel_launch(void* const* d_in, const int* in_sizes, int n_in,
                              void* d_out, int out_size, void* d_ws, size_t ws_size,
                              hipStream_t stream) {
    const float* x   = (const float*)d_in[0];
    const float* Wih = (const float*)d_in[1];
    const float* Whh = (const float*)d_in[2];
    const float* bih = (const float*)d_in[3];
    const float* bhh = (const float*)d_in[4];
    const float* h0  = (const float*)d_in[5];
    const float* c0  = (const float*)d_in[6];
    float* out = (float*)d_out;

    hipLaunchKernelGGL(lstm_chunks, dim3(GRID), dim3(BLOCK), 0, stream,
                       x, Wih, Whh, bih, bhh, h0, c0, out);
}

// Round 4
// 32.686 us; speedup vs baseline: 3.6727x; 1.3880x over previous
//
#include <hip/hip_runtime.h>

// LSTM, T=2^20, H=4. Speculative chunked scan (round 3).
//   - NCHUNK=32768 chunks of CHUNK=32 outputs; warm-start (h,c)=(0,0) WARM=64
//     steps earlier (clamped to 0). Contraction ~e^{-1.1/step} (absmax sat at
//     the bf16 floor 2^-8 for WARM=512 AND 128 -> enormous margin).
//   - 2048 waves = 2 waves/SIMD: the second wave fills the serial-chain
//     dependency stalls rocprof exposed in round 2 (VALUBusy 43%).
//   - One chunk per 4-lane quad; lane k owns hidden k. Cross-lane = 3 quad_perm
//     DPP broadcasts of h. W_hh pre-permuted per-lane (XOR) for static indexing.
//   - log2(e) folded into gate weights/bias: activations use raw v_exp_f32
//     (2^x) with the negate as a free source modifier; no input multiply.
//   - Normal (cached) stores: round-3 NT stores caused 3.7x HBM write
//     amplification (59 MB vs 16 MB) via scalar streaming sectors.

constexpr int T_LEN  = 1 << 20;
constexpr int CHUNK  = 32;
constexpr int WARM   = 64;
constexpr int NCHUNK = T_LEN / CHUNK;       // 32768
constexpr int BLOCK  = 64;
constexpr int GRID   = NCHUNK * 4 / BLOCK;  // 2048 waves = 2 per SIMD

constexpr float LOG2E  = 1.4426950408889634f;

// quad_perm DPP: xor1=[1,0,3,2]=0xB1, xor2=[2,3,0,1]=0x4E, xor3=[3,2,1,0]=0x1B
template <int CTRL>
__device__ __forceinline__ float qperm(float v) {
    int i = __float_as_int(v);
    i = __builtin_amdgcn_update_dpp(i, i, CTRL, 0xF, 0xF, false);
    return __int_as_float(i);
}

// zp is the gate pre-activation PRE-SCALED by log2(e): sigma(z) = 1/(1+2^-zp)
__device__ __forceinline__ float sigmoid_p(float zp) {
    return __builtin_amdgcn_rcpf(1.0f + __builtin_amdgcn_exp2f(-zp));
}
// zp pre-scaled by 2*log2(e): tanh(z) = 1 - 2/(1+2^zp)
__device__ __forceinline__ float tanh_p(float zp) {
    return __builtin_fmaf(-2.0f,
             __builtin_amdgcn_rcpf(1.0f + __builtin_amdgcn_exp2f(zp)), 1.0f);
}

struct LaneState { float hx0, hx1, hx2, hx3, c; };

__device__ __forceinline__ float lstm_step(
    const float4 xv,
    const float (&wih)[4][4], const float (&whh)[4][4], const float (&bias)[4],
    LaneState& s)
{
    // x-part first (operands prefetched, off the critical path).
    float g0 = __builtin_fmaf(wih[0][3], xv.w, __builtin_fmaf(wih[0][2], xv.z,
               __builtin_fmaf(wih[0][1], xv.y, __builtin_fmaf(wih[0][0], xv.x, bias[0]))));
    float g1 = __builtin_fmaf(wih[1][3], xv.w, __builtin_fmaf(wih[1][2], xv.z,
               __builtin_fmaf(wih[1][1], xv.y, __builtin_fmaf(wih[1][0], xv.x, bias[1]))));
    float g2 = __builtin_fmaf(wih[2][3], xv.w, __builtin_fmaf(wih[2][2], xv.z,
               __builtin_fmaf(wih[2][1], xv.y, __builtin_fmaf(wih[2][0], xv.x, bias[2]))));
    float g3 = __builtin_fmaf(wih[3][3], xv.w, __builtin_fmaf(wih[3][2], xv.z,
               __builtin_fmaf(wih[3][1], xv.y, __builtin_fmaf(wih[3][0], xv.x, bias[3]))));
    // h-part: critical path; hx0 (lane-local, ready first) leads the chain.
    g0 = __builtin_fmaf(whh[0][3], s.hx3, __builtin_fmaf(whh[0][2], s.hx2,
         __builtin_fmaf(whh[0][1], s.hx1, __builtin_fmaf(whh[0][0], s.hx0, g0))));
    g1 = __builtin_fmaf(whh[1][3], s.hx3, __builtin_fmaf(whh[1][2], s.hx2,
         __builtin_fmaf(whh[1][1], s.hx1, __builtin_fmaf(whh[1][0], s.hx0, g1))));
    g2 = __builtin_fmaf(whh[2][3], s.hx3, __builtin_fmaf(whh[2][2], s.hx2,
         __builtin_fmaf(whh[2][1], s.hx1, __builtin_fmaf(whh[2][0], s.hx0, g2))));
    g3 = __builtin_fmaf(whh[3][3], s.hx3, __builtin_fmaf(whh[3][2], s.hx2,
         __builtin_fmaf(whh[3][1], s.hx1, __builtin_fmaf(whh[3][0], s.hx0, g3))));

    const float i_ = sigmoid_p(g0);
    const float f_ = sigmoid_p(g1);
    const float gg = tanh_p(g2);
    const float o_ = sigmoid_p(g3);

    s.c = __builtin_fmaf(f_, s.c, i_ * gg);
    const float th = tanh_p(s.c * (2.0f * LOG2E));
    const float hk = o_ * th;

    s.hx0 = hk;
    s.hx1 = qperm<0xB1>(hk);
    s.hx2 = qperm<0x4E>(hk);
    s.hx3 = qperm<0x1B>(hk);
    return hk;
}

__global__ __launch_bounds__(BLOCK, 2) void lstm_chunks(
    const float* __restrict__ x,    // [T,4]
    const float* __restrict__ Wih,  // [16,4]
    const float* __restrict__ Whh,  // [16,4]
    const float* __restrict__ bih,  // [16]
    const float* __restrict__ bhh,  // [16]
    const float* __restrict__ h0,   // [4]
    const float* __restrict__ c0,   // [4]
    float* __restrict__ out)        // [T,4]
{
    const int tid   = blockIdx.x * BLOCK + threadIdx.x;
    const int lane  = tid & 3;
    const int chunk = tid >> 2;

    // Gate order (i,f,g,o) -> packed row r = t*4 + lane.
    // Scale: log2e for sigmoid gates (i,f,o), 2*log2e for the tanh gate (g).
    float wih[4][4], whh[4][4], bias[4];
#pragma unroll
    for (int t = 0; t < 4; ++t) {
        const float sc = (t == 2) ? (2.0f * LOG2E) : LOG2E;
        const int r = t * 4 + lane;
#pragma unroll
        for (int m = 0; m < 4; ++m) {
            wih[t][m] = sc * Wih[r * 4 + m];
            whh[t][m] = sc * Whh[r * 4 + (lane ^ m)];
        }
        bias[t] = sc * (bih[r] + bhh[r]);
    }

    const int tout0 = chunk * CHUNK;
    const int tend  = tout0 + CHUNK;
    int t0 = tout0 - WARM;
    if (t0 < 0) t0 = 0;             // early chunks start exactly at t=0

    LaneState s;
    if (t0 == 0) {
        s.hx0 = h0[lane];    s.hx1 = h0[lane ^ 1];
        s.hx2 = h0[lane ^ 2]; s.hx3 = h0[lane ^ 3];
        s.c = c0[lane];
    } else {
        s.hx0 = s.hx1 = s.hx2 = s.hx3 = 0.0f;
        s.c = 0.0f;
    }

    float4 bufA[4], bufB[4];
#pragma unroll
    for (int u = 0; u < 4; ++u)
        bufA[u] = *reinterpret_cast<const float4*>(x + 4 * (t0 + u));

    // ---- warmup (no stores). Trip count in {0, 32, 64}: multiple of 8. ----
    for (int tb = t0; tb < tout0; tb += 8) {
#pragma unroll
        for (int u = 0; u < 4; ++u)
            bufB[u] = *reinterpret_cast<const float4*>(x + 4 * (tb + 4 + u));
#pragma unroll
        for (int u = 0; u < 4; ++u) (void)lstm_step(bufA[u], wih, whh, bias, s);
#pragma unroll
        for (int u = 0; u < 4; ++u)
            bufA[u] = *reinterpret_cast<const float4*>(x + 4 * (tb + 8 + u));
#pragma unroll
        for (int u = 0; u < 4; ++u) (void)lstm_step(bufB[u], wih, whh, bias, s);
    }

    // ---- output loop: CHUNK=32 steps, unconditional cached stores. ----
    float* po = out + 4 * tout0 + lane;
    for (int tb = tout0; tb < tend; tb += 8) {
#pragma unroll
        for (int u = 0; u < 4; ++u) {
            int tn = tb + 4 + u;                    // clamp: only last chunk overruns
            tn = tn < T_LEN ? tn : T_LEN - 1;
            bufB[u] = *reinterpret_cast<const float4*>(x + 4 * tn);
        }
#pragma unroll
        for (int u = 0; u < 4; ++u) {
            const float hk = lstm_step(bufA[u], wih, whh, bias, s);
            po[4 * (tb - tout0 + u)] = hk;
        }
#pragma unroll
        for (int u = 0; u < 4; ++u) {
            int tn = tb + 8 + u;
            tn = tn < T_LEN ? tn : T_LEN - 1;
            bufA[u] = *reinterpret_cast<const float4*>(x + 4 * tn);
        }
#pragma unroll
        for (int u = 0; u < 4; ++u) {
            const float hk = lstm_step(bufB[u], wih, whh, bias, s);
            po[4 * (tb - tout0 + 4 + u)] = hk;
        }
    }
}

extern "C" void kernel_launch(void* const* d_in, const int* in_sizes, int n_in,
                              void* d_out, int out_size, void* d_ws, size_t ws_size,
                              hipStream_t stream) {
    const float* x   = (const float*)d_in[0];
    const float* Wih = (const float*)d_in[1];
    const float* Whh = (const float*)d_in[2];
    const float* bih = (const float*)d_in[3];
    const float* bhh = (const float*)d_in[4];
    const float* h0  = (const float*)d_in[5];
    const float* c0  = (const float*)d_in[6];
    float* out = (float*)d_out;

    hipLaunchKernelGGL(lstm_chunks, dim3(GRID), dim3(BLOCK), 0, stream,
                       x, Wih, Whh, bih, bhh, h0, c0, out);
}